// Round 9
// baseline (113.747 us; speedup 1.0000x reference)
//
#include <hip/hip_runtime.h>

// Capsule routing on MI355X — MEASUREMENT ROUND (R9).
// Identity: softmax over the capsule axis followed by a sum over that axis is
// identically 1 -> the routing loop is dead code and
//   out[b, o] = sum_i ( sum_t x[b,t,i] ) * W[i, o]
//
// R7 vs R8: two structurally different K1s time identically (73.5 vs 73.4)
// -> K1 is limited by something external to its loop structure, OR a fixed
// per-replay overhead masks kernel deltas. This round launches K1 TWICE
// (idempotent: writes the same part both times; deterministic). The total
// minus R7's 73.48 us directly measures K1(warm) + one node gap:
//   ~40-47 -> K1 at roofline, ~20 us fixed overhead exists
//   >=53   -> K1 itself is slow (not BW) -> attack its structure
//   <=30   -> L3 serves x, overhead dominates -> attack overhead
// K1/K2/K3 are byte-identical to R7 (proven 73.48 total).

#define BATCH   32
#define TLEN    2048
#define DIN     1024
#define DOUT    2048            // NUM_CAPSULE * DIM_CAPSULE
#define NCHUNK  64
#define RPC     (TLEN / NCHUNK) // 32 rows per chunk

// ---------------------------------------------------------------------------
// K1: partial column sums of x over T.  (byte-identical to R7)
// grid = (NCHUNK, BATCH) = 2048 blocks, 256 threads -> 32 waves/CU.
// ---------------------------------------------------------------------------
__global__ __launch_bounds__(256) void colsum_partial(
    const float* __restrict__ x, float* __restrict__ part)
{
    const int chunk = blockIdx.x;
    const int b     = blockIdx.y;
    const int tx    = threadIdx.x;

    const float4* base = reinterpret_cast<const float4*>(
        x + (size_t)b * TLEN * DIN + (size_t)chunk * RPC * DIN) + tx;

    float4 a0 = make_float4(0.f, 0.f, 0.f, 0.f);
    float4 a1 = make_float4(0.f, 0.f, 0.f, 0.f);
#pragma unroll 8
    for (int r = 0; r < RPC; r += 2) {
        float4 v0 = base[(size_t)r       * (DIN / 4)];
        float4 v1 = base[(size_t)(r + 1) * (DIN / 4)];
        a0.x += v0.x; a0.y += v0.y; a0.z += v0.z; a0.w += v0.w;
        a1.x += v1.x; a1.y += v1.y; a1.z += v1.z; a1.w += v1.w;
    }
    a0.x += a1.x; a0.y += a1.y; a0.z += a1.z; a0.w += a1.w;

    reinterpret_cast<float4*>(part + ((size_t)chunk * BATCH + b) * DIN)[tx] = a0;
}

// ---------------------------------------------------------------------------
// K2: reduce NCHUNK partials -> xs[b][i].  (byte-identical to R7)
// ---------------------------------------------------------------------------
__global__ __launch_bounds__(256) void chunk_reduce(
    const float* __restrict__ part, float* __restrict__ xs)
{
    const int seg = blockIdx.x;
    const int b   = blockIdx.y;
    const int i   = seg * 256 + threadIdx.x;

    float acc = 0.f;
#pragma unroll 8
    for (int c = 0; c < NCHUNK; ++c)
        acc += part[((size_t)c * BATCH + b) * DIN + i];
    xs[(size_t)b * DIN + i] = acc;
}

// ---------------------------------------------------------------------------
// K3: out[b, o] = sum_i xs[b][i] * W[i, o]  (byte-identical to R7)
// ---------------------------------------------------------------------------
__global__ __launch_bounds__(256) void matmul_small(
    const float* __restrict__ xs, const float* __restrict__ W,
    float* __restrict__ out)
{
    __shared__ float ps[4][4][64];   // [iq][bb][ol] = 4 KB

    const int cb = blockIdx.x;   // 0..31
    const int bg = blockIdx.y;   // 0..7
    const int tx = threadIdx.x;
    const int ol = tx & 63;
    const int iq = tx >> 6;      // wave id = i-segment
    const int o  = cb * 64 + ol;
    const int i0 = iq * 256;

    const float* wp = W + (size_t)i0 * DOUT + o;
    const float* x0 = xs + (size_t)(bg * 4 + 0) * DIN + i0;
    const float* x1 = xs + (size_t)(bg * 4 + 1) * DIN + i0;
    const float* x2 = xs + (size_t)(bg * 4 + 2) * DIN + i0;
    const float* x3 = xs + (size_t)(bg * 4 + 3) * DIN + i0;

    float a0 = 0.f, a1 = 0.f, a2 = 0.f, a3 = 0.f;
#pragma unroll 8
    for (int k = 0; k < 256; ++k) {
        const float w = wp[(size_t)k * DOUT];
        a0 += x0[k] * w;
        a1 += x1[k] * w;
        a2 += x2[k] * w;
        a3 += x3[k] * w;
    }
    ps[iq][0][ol] = a0;
    ps[iq][1][ol] = a1;
    ps[iq][2][ol] = a2;
    ps[iq][3][ol] = a3;
    __syncthreads();

    const int bb = tx >> 6;
    float s = ps[0][bb][ol] + ps[1][bb][ol] + ps[2][bb][ol] + ps[3][bb][ol];
    out[(size_t)(bg * 4 + bb) * DOUT + cb * 64 + ol] = s;
}

extern "C" void kernel_launch(void* const* d_in, const int* in_sizes, int n_in,
                              void* d_out, int out_size, void* d_ws, size_t ws_size,
                              hipStream_t stream)
{
    const float* x = (const float*)d_in[0];   // (32, 2048, 1024) f32
    const float* W = (const float*)d_in[1];   // (1024, 2048) f32
    float* out  = (float*)d_out;              // (32, 32, 64) f32 flat
    float* part = (float*)d_ws;                                // 8 MB
    float* xs   = (float*)d_ws + (size_t)NCHUNK * BATCH * DIN; // 128 KB

    dim3 g1(NCHUNK, BATCH);
    // PROBE: launch K1 twice (idempotent). Total - R7_total = K1(warm) + gap.
    colsum_partial<<<g1, 256, 0, stream>>>(x, part);
    colsum_partial<<<g1, 256, 0, stream>>>(x, part);

    dim3 g2(DIN / 256, BATCH);
    chunk_reduce<<<g2, 256, 0, stream>>>(part, xs);

    dim3 g3(32, 8);
    matmul_small<<<g3, 256, 0, stream>>>(xs, W, out);
}

// Round 10
// 73.709 us; speedup vs baseline: 1.5432x; 1.5432x over previous
//
#include <hip/hip_runtime.h>

// Capsule routing on MI355X — FINAL (R7 configuration restored after R9 probe).
// Identity: softmax over the capsule axis followed by a sum over that axis is
// identically 1 -> the routing loop is dead code and
//   out[b, o] = sum_i ( sum_t x[b,t,i] ) * W[i, o]
//
// Session model (R9 double-K1 probe):
//   fixed per-replay overhead ~28 us (harness graph launch+sync; node gaps
//   are ~0.3 us, so not addressable by fusion), K1 ~40 us = 6.4 TB/s
//   (>= 6.29 TB/s achievable HBM read ceiling -> ROOFLINE), K2 ~2.5, K3 ~3.
//   Fusing K2/K3 measurably regresses (R6: +6.5 us, redundant part traffic);
//   manual grid barriers are catastrophic (R5: 717 us).
//
//   K1 colsum_partial : x -> part[64][32][1024]       (HBM-bound, roofline)
//   K2 chunk_reduce   : part -> xs[32][1024], 128 blk
//   K3 matmul_small   : xs @ W -> out, 256 blk x 256  (no atomics)

#define BATCH   32
#define TLEN    2048
#define DIN     1024
#define DOUT    2048            // NUM_CAPSULE * DIM_CAPSULE
#define NCHUNK  64
#define RPC     (TLEN / NCHUNK) // 32 rows per chunk

// ---------------------------------------------------------------------------
// K1: partial column sums of x over T.
// grid = (NCHUNK, BATCH) = 2048 blocks, 256 threads -> 32 waves/CU.
// Measured at 6.4 TB/s (R9 probe) — HBM read roofline.
// ---------------------------------------------------------------------------
__global__ __launch_bounds__(256) void colsum_partial(
    const float* __restrict__ x, float* __restrict__ part)
{
    const int chunk = blockIdx.x;
    const int b     = blockIdx.y;
    const int tx    = threadIdx.x;

    const float4* base = reinterpret_cast<const float4*>(
        x + (size_t)b * TLEN * DIN + (size_t)chunk * RPC * DIN) + tx;

    float4 a0 = make_float4(0.f, 0.f, 0.f, 0.f);
    float4 a1 = make_float4(0.f, 0.f, 0.f, 0.f);
#pragma unroll 8
    for (int r = 0; r < RPC; r += 2) {
        float4 v0 = base[(size_t)r       * (DIN / 4)];
        float4 v1 = base[(size_t)(r + 1) * (DIN / 4)];
        a0.x += v0.x; a0.y += v0.y; a0.z += v0.z; a0.w += v0.w;
        a1.x += v1.x; a1.y += v1.y; a1.z += v1.z; a1.w += v1.w;
    }
    a0.x += a1.x; a0.y += a1.y; a0.z += a1.z; a0.w += a1.w;

    reinterpret_cast<float4*>(part + ((size_t)chunk * BATCH + b) * DIN)[tx] = a0;
}

// ---------------------------------------------------------------------------
// K2: reduce NCHUNK partials -> xs[b][i].
// grid = (DIN/256 = 4 segs, BATCH) = 128 blocks, 256 threads.
// ---------------------------------------------------------------------------
__global__ __launch_bounds__(256) void chunk_reduce(
    const float* __restrict__ part, float* __restrict__ xs)
{
    const int seg = blockIdx.x;
    const int b   = blockIdx.y;
    const int i   = seg * 256 + threadIdx.x;

    float acc = 0.f;
#pragma unroll 8
    for (int c = 0; c < NCHUNK; ++c)
        acc += part[((size_t)c * BATCH + b) * DIN + i];
    xs[(size_t)b * DIN + i] = acc;
}

// ---------------------------------------------------------------------------
// K3: out[b, o] = sum_i xs[b][i] * W[i, o] — no atomics, no memset.
// grid = (32 cb, 8 bg) = 256 blocks, 256 threads (4 waves).
// Wave iq covers i in [iq*256, iq*256+256); xs reads are wave-uniform ->
// scalar s_load path; W loads coalesced; 4-way LDS combine; single write.
// ---------------------------------------------------------------------------
__global__ __launch_bounds__(256) void matmul_small(
    const float* __restrict__ xs, const float* __restrict__ W,
    float* __restrict__ out)
{
    __shared__ float ps[4][4][64];   // [iq][bb][ol] = 4 KB

    const int cb = blockIdx.x;   // 0..31
    const int bg = blockIdx.y;   // 0..7
    const int tx = threadIdx.x;
    const int ol = tx & 63;
    const int iq = tx >> 6;      // wave id = i-segment
    const int o  = cb * 64 + ol;
    const int i0 = iq * 256;

    const float* wp = W + (size_t)i0 * DOUT + o;
    const float* x0 = xs + (size_t)(bg * 4 + 0) * DIN + i0;
    const float* x1 = xs + (size_t)(bg * 4 + 1) * DIN + i0;
    const float* x2 = xs + (size_t)(bg * 4 + 2) * DIN + i0;
    const float* x3 = xs + (size_t)(bg * 4 + 3) * DIN + i0;

    float a0 = 0.f, a1 = 0.f, a2 = 0.f, a3 = 0.f;
#pragma unroll 8
    for (int k = 0; k < 256; ++k) {
        const float w = wp[(size_t)k * DOUT];
        a0 += x0[k] * w;
        a1 += x1[k] * w;
        a2 += x2[k] * w;
        a3 += x3[k] * w;
    }
    ps[iq][0][ol] = a0;
    ps[iq][1][ol] = a1;
    ps[iq][2][ol] = a2;
    ps[iq][3][ol] = a3;
    __syncthreads();

    const int bb = tx >> 6;
    float s = ps[0][bb][ol] + ps[1][bb][ol] + ps[2][bb][ol] + ps[3][bb][ol];
    out[(size_t)(bg * 4 + bb) * DOUT + cb * 64 + ol] = s;
}

extern "C" void kernel_launch(void* const* d_in, const int* in_sizes, int n_in,
                              void* d_out, int out_size, void* d_ws, size_t ws_size,
                              hipStream_t stream)
{
    const float* x = (const float*)d_in[0];   // (32, 2048, 1024) f32
    const float* W = (const float*)d_in[1];   // (1024, 2048) f32
    float* out  = (float*)d_out;              // (32, 32, 64) f32 flat
    float* part = (float*)d_ws;                                // 8 MB
    float* xs   = (float*)d_ws + (size_t)NCHUNK * BATCH * DIN; // 128 KB

    dim3 g1(NCHUNK, BATCH);
    colsum_partial<<<g1, 256, 0, stream>>>(x, part);

    dim3 g2(DIN / 256, BATCH);
    chunk_reduce<<<g2, 256, 0, stream>>>(part, xs);

    dim3 g3(32, 8);
    matmul_small<<<g3, 256, 0, stream>>>(xs, W, out);
}